// Round 6
// baseline (362.692 us; speedup 1.0000x reference)
//
#include <hip/hip_runtime.h>
#include <hip/hip_bf16.h>

typedef __hip_bfloat16 bf16;
typedef __attribute__((ext_vector_type(8))) short short8;
typedef __attribute__((ext_vector_type(4))) short short4v;
typedef __attribute__((ext_vector_type(4))) float floatx4;

#define T_SEQ 4096
#define C_DIM 2048
#define NHEAD 16
#define HSZ   128
#define NGRP  4

#define MFMA_BF16(A,B,C) __builtin_amdgcn_mfma_f32_16x16x32_bf16((A),(B),(C),0,0,0)

__device__ __forceinline__ void gld_lds16(const bf16* g, bf16* l) {
  __builtin_amdgcn_global_load_lds(
      (__attribute__((address_space(1))) void*)(g),
      (__attribute__((address_space(3))) void*)(l), 16, 0, 0);
}

// fp32 -> bf16 cast, 8 elements/thread
__global__ void cvt_kernel(const float* __restrict__ src, bf16* __restrict__ dst, long n)
{
  const long i = ((long)blockIdx.x * blockDim.x + threadIdx.x) * 8;
  if (i >= n) return;
  const float4 a = *(const float4*)(src + i);
  const float4 b = *(const float4*)(src + i + 4);
  bf16 tmp[8];
  tmp[0] = __float2bfloat16(a.x); tmp[1] = __float2bfloat16(a.y);
  tmp[2] = __float2bfloat16(a.z); tmp[3] = __float2bfloat16(a.w);
  tmp[4] = __float2bfloat16(b.x); tmp[5] = __float2bfloat16(b.y);
  tmp[6] = __float2bfloat16(b.z); tmp[7] = __float2bfloat16(b.w);
  *(short8*)(dst + i) = *(const short8*)tmp;
}

// C = A (MxK) * B^T (NxK), bf16 in, fp32 accum.
// qkv_mode==1: N=3072, scatter bf16 to Q/K (row-major) and V^T (d-major) buffers.
// qkv_mode==0: fp32 output to Cf with ld = 2048 (proj GEMM).
__global__ __launch_bounds__(256, 2)
void gemm_bt_kernel(const bf16* __restrict__ A, const bf16* __restrict__ B,
                    float* __restrict__ Cf, bf16* __restrict__ Cq,
                    bf16* __restrict__ Ck, bf16* __restrict__ Cvt,
                    int K, int qkv_mode)
{
  __shared__ alignas(16) bf16 As[128 * 64];
  __shared__ alignas(16) bf16 Bs[128 * 64];

  const int t  = threadIdx.x;
  const int w  = t >> 6, l = t & 63;
  const int wr = w >> 1, wc = w & 1;
  const int q4 = l >> 4, ln = l & 15;
  const long bm = (long)blockIdx.y * 128;
  const long bn = (long)blockIdx.x * 128;

  floatx4 acc[4][4] = {};

  const bf16* Ab = A + (bm + t / 8) * (long)K + (t % 8) * 8;
  const bf16* Bb = B + (bn + t / 8) * (long)K + (t % 8) * 8;

  for (int k0 = 0; k0 < K; k0 += 64) {
    __syncthreads();
#pragma unroll
    for (int i = 0; i < 4; ++i) {
      gld_lds16(Ab + (long)i * 32 * K + k0, As + (i * 256 + w * 64) * 8);
      gld_lds16(Bb + (long)i * 32 * K + k0, Bs + (i * 256 + w * 64) * 8);
    }
    __syncthreads();
#pragma unroll
    for (int kk = 0; kk < 64; kk += 32) {
      short8 af[4], bfr[4];
      const int co = kk + q4 * 8;
#pragma unroll
      for (int mi = 0; mi < 4; ++mi)
        af[mi] = *(const short8*)(As + (wr * 64 + mi * 16 + ln) * 64 + co);
#pragma unroll
      for (int ni = 0; ni < 4; ++ni)
        bfr[ni] = *(const short8*)(Bs + (wc * 64 + ni * 16 + ln) * 64 + co);
#pragma unroll
      for (int mi = 0; mi < 4; ++mi)
#pragma unroll
        for (int ni = 0; ni < 4; ++ni)
          acc[mi][ni] = MFMA_BF16(af[mi], bfr[ni], acc[mi][ni]);
    }
  }

  if (!qkv_mode) {
#pragma unroll
    for (int mi = 0; mi < 4; ++mi) {
      const long r0 = bm + wr * 64 + mi * 16 + q4 * 4;
#pragma unroll
      for (int ni = 0; ni < 4; ++ni) {
        const long c = bn + wc * 64 + ni * 16 + ln;
#pragma unroll
        for (int r = 0; r < 4; ++r)
          Cf[(r0 + r) * C_DIM + c] = acc[mi][ni][r];
      }
    }
  } else {
    const int cb = blockIdx.x;
    const int g = cb / 6, slot = cb - g * 6;
    if (slot == 5) {
      // V^T: [d][t], d-major per group
      bf16* dstv = Cvt + (long)g * HSZ * T_SEQ;
#pragma unroll
      for (int mi = 0; mi < 4; ++mi) {
        const long r0 = bm + wr * 64 + mi * 16 + q4 * 4;   // t base (mult of 4)
#pragma unroll
        for (int ni = 0; ni < 4; ++ni) {
          const long c = wc * 64 + ni * 16 + ln;           // d
          short4v pk;
#pragma unroll
          for (int r = 0; r < 4; ++r) {
            bf16 v = __float2bfloat16(acc[mi][ni][r]);
            pk[r] = *(short*)&v;
          }
          *(short4v*)(dstv + c * T_SEQ + r0) = pk;
        }
      }
    } else {
      bf16* dst = (slot < 4) ? (Cq + (long)(g * 4 + slot) * T_SEQ * HSZ)
                             : (Ck + (long)g * T_SEQ * HSZ);
#pragma unroll
      for (int mi = 0; mi < 4; ++mi) {
        const long r0 = bm + wr * 64 + mi * 16 + q4 * 4;
#pragma unroll
        for (int ni = 0; ni < 4; ++ni) {
          const long c = wc * 64 + ni * 16 + ln;
#pragma unroll
          for (int r = 0; r < 4; ++r)
            dst[(r0 + r) * HSZ + c] = __float2bfloat16(acc[mi][ni][r]);
        }
      }
    }
  }
}

// In-place RoPE. Q additionally folded with scale*log2(e) (attention uses exp2).
__global__ void rope_kernel(bf16* __restrict__ Q, bf16* __restrict__ Kb,
                            const float* __restrict__ cs, const float* __restrict__ sn)
{
  const long idx = (long)blockIdx.x * blockDim.x + threadIdx.x;
  const long NQ = (long)NHEAD * T_SEQ * 64;
  bf16* buf; long rem; float qs;
  if (idx < NQ) { buf = Q;  rem = idx;      qs = 0.08838834764831845f * 1.4426950408889634f; }
  else          { buf = Kb; rem = idx - NQ; qs = 1.0f; }
  const int d  = (int)(rem & 63);
  const int tt = (int)((rem >> 6) & (T_SEQ - 1));
  const int hh = (int)(rem >> 18);
  const float c = cs[tt * 64 + d];
  const float s = sn[tt * 64 + d];
  bf16* p = buf + ((long)hh * T_SEQ + tt) * HSZ + d;
  const float x1 = __bfloat162float(p[0]);
  const float x2 = __bfloat162float(p[64]);
  p[0]  = __float2bfloat16((x1 * c - x2 * s) * qs);
  p[64] = __float2bfloat16((x2 * c + x1 * s) * qs);
}

// Causal flash attention, GQA 4:1. BQ=128 (4 waves x 32 rows), BKV=64.
// One block per q-tile PAIR (i, 31-i): exactly 66 j-tiles per block — dispatch-proof
// balance. LDS double-buffer (84 KB) forces 1 block/CU and gives 1 barrier/tile.
__global__ __launch_bounds__(256, 1)
void attn_kernel(const bf16* __restrict__ Qg, const bf16* __restrict__ Kg,
                 const bf16* __restrict__ Vtg, bf16* __restrict__ Y)
{
  __shared__ alignas(16) bf16 Ks[2][64][132];   // 33.0 KB (buf stride = 0 mod 32 banks)
  __shared__ alignas(16) bf16 Vt[2][128][68];   // 34.0 KB
  __shared__ alignas(16) bf16 Ps[128][68];      // 17.0 KB -> 84 KB total: 1 block/CU

  const int h = blockIdx.y;
  const int g = h >> 2;
  const int t = threadIdx.x;
  const int w = t >> 6, l = t & 63;
  const int q4 = l >> 4, ln = l & 15;

  const bf16* Qh = Qg + (long)h * T_SEQ * HSZ;
  const bf16* Kh = Kg + (long)g * T_SEQ * HSZ;
  const bf16* Vh = Vtg + (long)g * HSZ * T_SEQ;   // [d][t]

  // staging addressing: K tile row=(t>>4)+16i, col=(t&15)*8 ; V tile d=(t>>3)+32i, s=(t&7)*8
  const int krow = t >> 4, kc = (t & 15) * 8;
  const int vrow = t >> 3, vc = (t & 7) * 8;

  // ones B-frag: B[n==0][k] = 1.0 -> MFMA produces row sums in column 0
  short8 ones_f;
#pragma unroll
  for (int i = 0; i < 8; ++i) ones_f[i] = (ln == 0) ? (short)0x3F80 : (short)0;

#pragma unroll 1
  for (int ph = 0; ph < 2; ++ph) {
    const int p = ph ? (31 - blockIdx.x) : blockIdx.x;
    const int qbase = p * 128 + w * 32;
    const int jmax = 2 * p + 1;   // >= 1 always

    // Q A-frags (Q pre-scaled by scale*log2e in rope_kernel)
    short8 qf[2][4];
#pragma unroll
    for (int mi = 0; mi < 2; ++mi) {
      const long row = qbase + mi * 16 + ln;
#pragma unroll
      for (int ks = 0; ks < 4; ++ks)
        qf[mi][ks] = *(const short8*)(Qh + row * HSZ + ks * 32 + q4 * 8);
    }

    floatx4 acc[2][8] = {};
    floatx4 acc_l[2] = {};

    // prime: tile 0 -> regs; (phase barrier); regs -> buf0; issue tile 1 loads
    short8 kpre[4], vpre[4];
#pragma unroll
    for (int i = 0; i < 4; ++i) {
      kpre[i] = *(const short8*)(Kh + (long)(krow + 16 * i) * HSZ + kc);
      vpre[i] = *(const short8*)(Vh + (long)(vrow + 32 * i) * T_SEQ + vc);
    }
    __syncthreads();   // prev phase's waves done reading all LDS buffers
#pragma unroll
    for (int i = 0; i < 4; ++i) {
      *(short8*)(&Ks[0][krow + 16 * i][kc]) = kpre[i];
      *(short8*)(&Vt[0][vrow + 32 * i][vc]) = vpre[i];
    }
#pragma unroll
    for (int i = 0; i < 4; ++i) {
      kpre[i] = *(const short8*)(Kh + (long)(64 + krow + 16 * i) * HSZ + kc);
      vpre[i] = *(const short8*)(Vh + (long)(vrow + 32 * i) * T_SEQ + 64 + vc);
    }

#pragma unroll 1
    for (int j = 0; j <= jmax; ++j) {
      const int s0 = j * 64;
      const int cur = j & 1;
      __syncthreads();   // buf[cur] writes (iter j-1 / prologue) complete everywhere

      // stage tile j+1 into the other buffer; issue global prefetch of tile j+2
      if (j < jmax) {
        const int nxt = cur ^ 1;
#pragma unroll
        for (int i = 0; i < 4; ++i) {
          *(short8*)(&Ks[nxt][krow + 16 * i][kc]) = kpre[i];
          *(short8*)(&Vt[nxt][vrow + 32 * i][vc]) = vpre[i];
        }
        if (j + 1 < jmax) {
          const int s2 = s0 + 128;
#pragma unroll
          for (int i = 0; i < 4; ++i) {
            kpre[i] = *(const short8*)(Kh + (long)(s2 + krow + 16 * i) * HSZ + kc);
            vpre[i] = *(const short8*)(Vh + (long)(vrow + 32 * i) * T_SEQ + s2 + vc);
          }
        }
      }

      // S = Q K^T (32 rows x 64 cols per wave)
      floatx4 sacc[2][4] = {};
#pragma unroll
      for (int ks = 0; ks < 4; ++ks) {
        short8 kf[4];
#pragma unroll
        for (int ni = 0; ni < 4; ++ni)
          kf[ni] = *(const short8*)(&Ks[cur][ni * 16 + ln][ks * 32 + q4 * 8]);
#pragma unroll
        for (int mi = 0; mi < 2; ++mi)
#pragma unroll
          for (int ni = 0; ni < 4; ++ni)
            sacc[mi][ni] = MFMA_BF16(qf[mi][ks], kf[ni], sacc[mi][ni]);
      }

      // p = exp2(s) with causal zeroing; write to Ps (wave-private rows, no barrier)
#pragma unroll
      for (int mi = 0; mi < 2; ++mi) {
        const int base_m = qbase + mi * 16 + q4 * 4 - s0 - ln;  // keep iff base_m+r-ni*16 >= 0
#pragma unroll
        for (int ni = 0; ni < 4; ++ni)
#pragma unroll
          for (int r = 0; r < 4; ++r) {
            float pv = __builtin_amdgcn_exp2f(sacc[mi][ni][r]);
            if (base_m + r - ni * 16 < 0) pv = 0.f;
            Ps[w * 32 + mi * 16 + q4 * 4 + r][ni * 16 + ln] = __float2bfloat16(pv);
          }
      }

      // O += P V ; l += P * ones
#pragma unroll
      for (int ks = 0; ks < 2; ++ks) {
        short8 pf[2], vf[8];
#pragma unroll
        for (int mi = 0; mi < 2; ++mi)
          pf[mi] = *(const short8*)(&Ps[w * 32 + mi * 16 + ln][ks * 32 + q4 * 8]);
#pragma unroll
        for (int nd = 0; nd < 8; ++nd)
          vf[nd] = *(const short8*)(&Vt[cur][nd * 16 + ln][ks * 32 + q4 * 8]);
#pragma unroll
        for (int mi = 0; mi < 2; ++mi) {
          acc_l[mi] = MFMA_BF16(pf[mi], ones_f, acc_l[mi]);
#pragma unroll
          for (int nd = 0; nd < 8; ++nd)
            acc[mi][nd] = MFMA_BF16(pf[mi], vf[nd], acc[mi][nd]);
        }
      }
    }

    // epilogue: broadcast l from column-0 lanes, normalize, store Y[t][h*128+d]
#pragma unroll
    for (int mi = 0; mi < 2; ++mi) {
#pragma unroll
      for (int r = 0; r < 4; ++r) {
        const float lv = __shfl(acc_l[mi][r], l & 48, 64);
        const float inv = (lv > 0.f) ? 1.f / lv : 0.f;
        const long tq = qbase + mi * 16 + q4 * 4 + r;
#pragma unroll
        for (int nd = 0; nd < 8; ++nd)
          Y[tq * C_DIM + h * HSZ + nd * 16 + ln] = __float2bfloat16(acc[mi][nd][r] * inv);
      }
    }
  }
}

extern "C" void kernel_launch(void* const* d_in, const int* in_sizes, int n_in,
                              void* d_out, int out_size, void* d_ws, size_t ws_size,
                              hipStream_t stream)
{
  const float* x  = (const float*)d_in[0];
  const float* cs = (const float*)d_in[1];
  const float* sn = (const float*)d_in[2];
  const float* Wa = (const float*)d_in[3];
  const float* Wp = (const float*)d_in[4];
  float* out = (float*)d_out;

  const long nx  = (long)T_SEQ * C_DIM;
  const long nwa = (long)(NHEAD + 2 * NGRP) * HSZ * C_DIM;
  const long nwp = (long)C_DIM * C_DIM;
  const long nqh = (long)NHEAD * T_SEQ * HSZ;
  const long nkg = (long)NGRP * T_SEQ * HSZ;

  const size_t need = (size_t)(nx + nwa + nqh + 2 * nkg + nqh) * sizeof(bf16);
  if (ws_size < need) return;

  bf16* xb  = (bf16*)d_ws;
  bf16* Wab = xb + nx;
  bf16* Q   = Wab + nwa;
  bf16* K   = Q + nqh;
  bf16* Vt  = K + nkg;      // V^T: [g][d][t]
  bf16* Y   = Vt + nkg;
  bf16* Wpb = xb;           // reuse: xb dead after QKV GEMM

  cvt_kernel<<<(int)(nx  / 8 / 256), 256, 0, stream>>>(x,  xb,  nx);
  cvt_kernel<<<(int)(nwa / 8 / 256), 256, 0, stream>>>(Wa, Wab, nwa);
  gemm_bt_kernel<<<dim3(24, 32), 256, 0, stream>>>(xb, Wab, nullptr, Q, K, Vt, C_DIM, 1);
  rope_kernel<<<20480, 256, 0, stream>>>(Q, K, cs, sn);
  attn_kernel<<<dim3(16, NHEAD), 256, 0, stream>>>(Q, K, Vt, Y);
  cvt_kernel<<<(int)(nwp / 8 / 256), 256, 0, stream>>>(Wp, Wpb, nwp);
  gemm_bt_kernel<<<dim3(16, 32), 256, 0, stream>>>(Y, Wpb, out, nullptr, nullptr, nullptr, C_DIM, 0);
}

// Round 7
// 351.695 us; speedup vs baseline: 1.0313x; 1.0313x over previous
//
#include <hip/hip_runtime.h>
#include <hip/hip_bf16.h>

typedef __hip_bfloat16 bf16;
typedef __attribute__((ext_vector_type(8))) short short8;
typedef __attribute__((ext_vector_type(4))) short short4v;
typedef __attribute__((ext_vector_type(4))) float floatx4;

#define T_SEQ 4096
#define C_DIM 2048
#define NHEAD 16
#define HSZ   128
#define NGRP  4

#define MFMA_BF16(A,B,C) __builtin_amdgcn_mfma_f32_16x16x32_bf16((A),(B),(C),0,0,0)

__device__ __forceinline__ void gld_lds16(const bf16* g, bf16* l) {
  __builtin_amdgcn_global_load_lds(
      (__attribute__((address_space(1))) void*)(g),
      (__attribute__((address_space(3))) void*)(l), 16, 0, 0);
}

// fp32 -> bf16 cast, 8 elements/thread
__global__ void cvt_kernel(const float* __restrict__ src, bf16* __restrict__ dst, long n)
{
  const long i = ((long)blockIdx.x * blockDim.x + threadIdx.x) * 8;
  if (i >= n) return;
  const float4 a = *(const float4*)(src + i);
  const float4 b = *(const float4*)(src + i + 4);
  bf16 tmp[8];
  tmp[0] = __float2bfloat16(a.x); tmp[1] = __float2bfloat16(a.y);
  tmp[2] = __float2bfloat16(a.z); tmp[3] = __float2bfloat16(a.w);
  tmp[4] = __float2bfloat16(b.x); tmp[5] = __float2bfloat16(b.y);
  tmp[6] = __float2bfloat16(b.z); tmp[7] = __float2bfloat16(b.w);
  *(short8*)(dst + i) = *(const short8*)tmp;
}

// C = A (MxK) * B^T (NxK), bf16 in, fp32 accum.
// qkv_mode==1: N=3072, scatter bf16 to Q/K (row-major) and V^T (d-major) buffers.
// qkv_mode==0: fp32 output to Cf with ld = 2048 (proj GEMM).
__global__ __launch_bounds__(256, 2)
void gemm_bt_kernel(const bf16* __restrict__ A, const bf16* __restrict__ B,
                    float* __restrict__ Cf, bf16* __restrict__ Cq,
                    bf16* __restrict__ Ck, bf16* __restrict__ Cvt,
                    int K, int qkv_mode)
{
  __shared__ alignas(16) bf16 As[128 * 64];
  __shared__ alignas(16) bf16 Bs[128 * 64];

  const int t  = threadIdx.x;
  const int w  = t >> 6, l = t & 63;
  const int wr = w >> 1, wc = w & 1;
  const int q4 = l >> 4, ln = l & 15;
  const long bm = (long)blockIdx.y * 128;
  const long bn = (long)blockIdx.x * 128;

  floatx4 acc[4][4] = {};

  const bf16* Ab = A + (bm + t / 8) * (long)K + (t % 8) * 8;
  const bf16* Bb = B + (bn + t / 8) * (long)K + (t % 8) * 8;

  for (int k0 = 0; k0 < K; k0 += 64) {
    __syncthreads();
#pragma unroll
    for (int i = 0; i < 4; ++i) {
      gld_lds16(Ab + (long)i * 32 * K + k0, As + (i * 256 + w * 64) * 8);
      gld_lds16(Bb + (long)i * 32 * K + k0, Bs + (i * 256 + w * 64) * 8);
    }
    __syncthreads();
#pragma unroll
    for (int kk = 0; kk < 64; kk += 32) {
      short8 af[4], bfr[4];
      const int co = kk + q4 * 8;
#pragma unroll
      for (int mi = 0; mi < 4; ++mi)
        af[mi] = *(const short8*)(As + (wr * 64 + mi * 16 + ln) * 64 + co);
#pragma unroll
      for (int ni = 0; ni < 4; ++ni)
        bfr[ni] = *(const short8*)(Bs + (wc * 64 + ni * 16 + ln) * 64 + co);
#pragma unroll
      for (int mi = 0; mi < 4; ++mi)
#pragma unroll
        for (int ni = 0; ni < 4; ++ni)
          acc[mi][ni] = MFMA_BF16(af[mi], bfr[ni], acc[mi][ni]);
    }
  }

  if (!qkv_mode) {
#pragma unroll
    for (int mi = 0; mi < 4; ++mi) {
      const long r0 = bm + wr * 64 + mi * 16 + q4 * 4;
#pragma unroll
      for (int ni = 0; ni < 4; ++ni) {
        const long c = bn + wc * 64 + ni * 16 + ln;
#pragma unroll
        for (int r = 0; r < 4; ++r)
          Cf[(r0 + r) * C_DIM + c] = acc[mi][ni][r];
      }
    }
  } else {
    const int cb = blockIdx.x;
    const int g = cb / 6, slot = cb - g * 6;
    if (slot == 5) {
      // V^T: [d][t], d-major per group
      bf16* dstv = Cvt + (long)g * HSZ * T_SEQ;
#pragma unroll
      for (int mi = 0; mi < 4; ++mi) {
        const long r0 = bm + wr * 64 + mi * 16 + q4 * 4;   // t base (mult of 4)
#pragma unroll
        for (int ni = 0; ni < 4; ++ni) {
          const long c = wc * 64 + ni * 16 + ln;           // d
          short4v pk;
#pragma unroll
          for (int r = 0; r < 4; ++r) {
            bf16 v = __float2bfloat16(acc[mi][ni][r]);
            pk[r] = *(short*)&v;
          }
          *(short4v*)(dstv + c * T_SEQ + r0) = pk;
        }
      }
    } else {
      bf16* dst = (slot < 4) ? (Cq + (long)(g * 4 + slot) * T_SEQ * HSZ)
                             : (Ck + (long)g * T_SEQ * HSZ);
#pragma unroll
      for (int mi = 0; mi < 4; ++mi) {
        const long r0 = bm + wr * 64 + mi * 16 + q4 * 4;
#pragma unroll
        for (int ni = 0; ni < 4; ++ni) {
          const long c = wc * 64 + ni * 16 + ln;
#pragma unroll
          for (int r = 0; r < 4; ++r)
            dst[(r0 + r) * HSZ + c] = __float2bfloat16(acc[mi][ni][r]);
        }
      }
    }
  }
}

// In-place RoPE. Q additionally folded with scale*log2(e) (attention uses exp2).
__global__ void rope_kernel(bf16* __restrict__ Q, bf16* __restrict__ Kb,
                            const float* __restrict__ cs, const float* __restrict__ sn)
{
  const long idx = (long)blockIdx.x * blockDim.x + threadIdx.x;
  const long NQ = (long)NHEAD * T_SEQ * 64;
  bf16* buf; long rem; float qs;
  if (idx < NQ) { buf = Q;  rem = idx;      qs = 0.08838834764831845f * 1.4426950408889634f; }
  else          { buf = Kb; rem = idx - NQ; qs = 1.0f; }
  const int d  = (int)(rem & 63);
  const int tt = (int)((rem >> 6) & (T_SEQ - 1));
  const int hh = (int)(rem >> 18);
  const float c = cs[tt * 64 + d];
  const float s = sn[tt * 64 + d];
  bf16* p = buf + ((long)hh * T_SEQ + tt) * HSZ + d;
  const float x1 = __bfloat162float(p[0]);
  const float x2 = __bfloat162float(p[64]);
  p[0]  = __float2bfloat16((x1 * c - x2 * s) * qs);
  p[64] = __float2bfloat16((x2 * c + x1 * s) * qs);
}

// Causal flash attention, GQA 4:1. BQ=128 (8 waves x 16 rows), BKV=64.
// One block per q-tile PAIR (i, 31-i): exactly 66 j-tiles per block — dispatch-proof
// balance. 512 threads (2 waves/SIMD) for latency hiding; 84 KB LDS dbuf -> 1 block/CU.
__global__ __launch_bounds__(512, 1)
void attn_kernel(const bf16* __restrict__ Qg, const bf16* __restrict__ Kg,
                 const bf16* __restrict__ Vtg, bf16* __restrict__ Y)
{
  __shared__ alignas(16) bf16 Ks[2][64][132];   // 33.0 KB
  __shared__ alignas(16) bf16 Vt[2][128][68];   // 34.0 KB
  __shared__ alignas(16) bf16 Ps[128][68];      // 17.0 KB -> 84 KB: 1 block/CU, 8 waves

  const int h = blockIdx.y;
  const int g = h >> 2;
  const int t = threadIdx.x;
  const int w = t >> 6, l = t & 63;
  const int q4 = l >> 4, ln = l & 15;

  const bf16* Qh = Qg + (long)h * T_SEQ * HSZ;
  const bf16* Kh = Kg + (long)g * T_SEQ * HSZ;
  const bf16* Vh = Vtg + (long)g * HSZ * T_SEQ;   // [d][t]

  // staging (512 thr, 2 rounds): K row=(v>>4), col=(v&15)*8 ; V d=(v>>3), s=(v&7)*8
  const int kr0 = t >> 4, kc = (t & 15) * 8;     // kr0: 0..31
  const int vr0 = t >> 3, vc = (t & 7) * 8;      // vr0: 0..63

  // ones B-frag: B[n==0][k] = 1.0 -> MFMA produces row sums in column 0
  short8 ones_f;
#pragma unroll
  for (int i = 0; i < 8; ++i) ones_f[i] = (ln == 0) ? (short)0x3F80 : (short)0;

#pragma unroll 1
  for (int ph = 0; ph < 2; ++ph) {
    const int p = ph ? (31 - blockIdx.x) : blockIdx.x;
    const int qbase = p * 128 + w * 16;          // wave owns 16 q-rows
    const int jmax = 2 * p + 1;                  // >= 1 always

    // Q A-frags (Q pre-scaled by scale*log2e in rope_kernel)
    short8 qf[4];
    {
      const long row = qbase + ln;
#pragma unroll
      for (int ks = 0; ks < 4; ++ks)
        qf[ks] = *(const short8*)(Qh + row * HSZ + ks * 32 + q4 * 8);
    }

    floatx4 acc[8] = {};
    floatx4 acc_l = {};

    // prime: tile 0 -> regs; (phase barrier); regs -> buf0; issue tile 1 loads
    short8 kpre[2], vpre[2];
#pragma unroll
    for (int i = 0; i < 2; ++i) {
      kpre[i] = *(const short8*)(Kh + (long)(kr0 + 32 * i) * HSZ + kc);
      vpre[i] = *(const short8*)(Vh + (long)(vr0 + 64 * i) * T_SEQ + vc);
    }
    __syncthreads();   // prev phase's waves done reading all LDS buffers
#pragma unroll
    for (int i = 0; i < 2; ++i) {
      *(short8*)(&Ks[0][kr0 + 32 * i][kc]) = kpre[i];
      *(short8*)(&Vt[0][vr0 + 64 * i][vc]) = vpre[i];
    }
#pragma unroll
    for (int i = 0; i < 2; ++i) {
      kpre[i] = *(const short8*)(Kh + (long)(64 + kr0 + 32 * i) * HSZ + kc);
      vpre[i] = *(const short8*)(Vh + (long)(vr0 + 64 * i) * T_SEQ + 64 + vc);
    }

#pragma unroll 1
    for (int j = 0; j <= jmax; ++j) {
      const int s0 = j * 64;
      const int cur = j & 1;
      __syncthreads();   // buf[cur] writes (iter j-1 / prologue) complete everywhere

      // stage tile j+1 into the other buffer; issue global prefetch of tile j+2
      if (j < jmax) {
        const int nxt = cur ^ 1;
#pragma unroll
        for (int i = 0; i < 2; ++i) {
          *(short8*)(&Ks[nxt][kr0 + 32 * i][kc]) = kpre[i];
          *(short8*)(&Vt[nxt][vr0 + 64 * i][vc]) = vpre[i];
        }
        if (j + 1 < jmax) {
          const int s2 = s0 + 128;
#pragma unroll
          for (int i = 0; i < 2; ++i) {
            kpre[i] = *(const short8*)(Kh + (long)(s2 + kr0 + 32 * i) * HSZ + kc);
            vpre[i] = *(const short8*)(Vh + (long)(vr0 + 64 * i) * T_SEQ + s2 + vc);
          }
        }
      }

      // S = Q K^T (16 rows x 64 cols per wave)
      floatx4 sacc[4] = {};
#pragma unroll
      for (int ks = 0; ks < 4; ++ks) {
        short8 kf[4];
#pragma unroll
        for (int ni = 0; ni < 4; ++ni)
          kf[ni] = *(const short8*)(&Ks[cur][ni * 16 + ln][ks * 32 + q4 * 8]);
#pragma unroll
        for (int ni = 0; ni < 4; ++ni)
          sacc[ni] = MFMA_BF16(qf[ks], kf[ni], sacc[ni]);
      }

      // p = exp2(s) with causal zeroing; write to Ps (wave-private rows, no barrier)
      {
        const int base_m = qbase + q4 * 4 - s0 - ln;  // keep iff base_m + r - ni*16 >= 0
#pragma unroll
        for (int ni = 0; ni < 4; ++ni)
#pragma unroll
          for (int r = 0; r < 4; ++r) {
            float pv = __builtin_amdgcn_exp2f(sacc[ni][r]);
            if (base_m + r - ni * 16 < 0) pv = 0.f;
            Ps[w * 16 + q4 * 4 + r][ni * 16 + ln] = __float2bfloat16(pv);
          }
      }

      // O += P V ; l += P * ones
#pragma unroll
      for (int ks = 0; ks < 2; ++ks) {
        short8 pf, vf[8];
        pf = *(const short8*)(&Ps[w * 16 + ln][ks * 32 + q4 * 8]);
#pragma unroll
        for (int nd = 0; nd < 8; ++nd)
          vf[nd] = *(const short8*)(&Vt[cur][nd * 16 + ln][ks * 32 + q4 * 8]);
        acc_l = MFMA_BF16(pf, ones_f, acc_l);
#pragma unroll
        for (int nd = 0; nd < 8; ++nd)
          acc[nd] = MFMA_BF16(pf, vf[nd], acc[nd]);
      }
    }

    // epilogue: broadcast l from column-0 lanes, normalize, store Y[t][h*128+d]
#pragma unroll
    for (int r = 0; r < 4; ++r) {
      const float lv = __shfl(acc_l[r], l & 48, 64);
      const float inv = (lv > 0.f) ? 1.f / lv : 0.f;
      const long tq = qbase + q4 * 4 + r;
#pragma unroll
      for (int nd = 0; nd < 8; ++nd)
        Y[tq * C_DIM + h * HSZ + nd * 16 + ln] = __float2bfloat16(acc[nd][r] * inv);
    }
  }
}

extern "C" void kernel_launch(void* const* d_in, const int* in_sizes, int n_in,
                              void* d_out, int out_size, void* d_ws, size_t ws_size,
                              hipStream_t stream)
{
  const float* x  = (const float*)d_in[0];
  const float* cs = (const float*)d_in[1];
  const float* sn = (const float*)d_in[2];
  const float* Wa = (const float*)d_in[3];
  const float* Wp = (const float*)d_in[4];
  float* out = (float*)d_out;

  const long nx  = (long)T_SEQ * C_DIM;
  const long nwa = (long)(NHEAD + 2 * NGRP) * HSZ * C_DIM;
  const long nwp = (long)C_DIM * C_DIM;
  const long nqh = (long)NHEAD * T_SEQ * HSZ;
  const long nkg = (long)NGRP * T_SEQ * HSZ;

  const size_t need = (size_t)(nx + nwa + nqh + 2 * nkg + nqh) * sizeof(bf16);
  if (ws_size < need) return;

  bf16* xb  = (bf16*)d_ws;
  bf16* Wab = xb + nx;
  bf16* Q   = Wab + nwa;
  bf16* K   = Q + nqh;
  bf16* Vt  = K + nkg;      // V^T: [g][d][t]
  bf16* Y   = Vt + nkg;
  bf16* Wpb = xb;           // reuse: xb dead after QKV GEMM

  cvt_kernel<<<(int)(nx  / 8 / 256), 256, 0, stream>>>(x,  xb,  nx);
  cvt_kernel<<<(int)(nwa / 8 / 256), 256, 0, stream>>>(Wa, Wab, nwa);
  gemm_bt_kernel<<<dim3(24, 32), 256, 0, stream>>>(xb, Wab, nullptr, Q, K, Vt, C_DIM, 1);
  rope_kernel<<<20480, 256, 0, stream>>>(Q, K, cs, sn);
  attn_kernel<<<dim3(16, NHEAD), 512, 0, stream>>>(Q, K, Vt, Y);
  cvt_kernel<<<(int)(nwp / 8 / 256), 256, 0, stream>>>(Wp, Wpb, nwp);
  gemm_bt_kernel<<<dim3(16, 32), 256, 0, stream>>>(Y, Wpb, out, nullptr, nullptr, nullptr, C_DIM, 0);
}